// Round 8
// baseline (542.142 us; speedup 1.0000x reference)
//
#include <hip/hip_runtime.h>

typedef unsigned short u16;
typedef __attribute__((ext_vector_type(8))) short short8;
typedef __attribute__((ext_vector_type(4))) unsigned short ushort4v;
typedef __attribute__((ext_vector_type(4))) float float4v;

__device__ __forceinline__ float bf2f(u16 u) {
  union { unsigned int i; float f; } c; c.i = ((unsigned int)u) << 16; return c.f;
}
__device__ __forceinline__ u16 f2bf(float f) {
  union { float f; unsigned int i; } c; c.f = f;
  unsigned int u = c.i;
  return (u16)((u + 0x7fffu + ((u >> 16) & 1u)) >> 16);
}
__device__ __forceinline__ float gelu_new(float x) {
  const float c = 0.7978845608028654f;
  float t = tanhf(c * (x + 0.044715f * x * x * x));
  return 0.5f * x * (1.0f + t);
}
__device__ __forceinline__ float ldres(const float* p) { return *p; }
__device__ __forceinline__ float ldres(const u16* p) { return bf2f(*p); }

__device__ __forceinline__ void gload_lds16(const u16* g, u16* l) {
  __builtin_amdgcn_global_load_lds(
      (const __attribute__((address_space(1))) unsigned int*)g,
      (__attribute__((address_space(3))) unsigned int*)l, 16, 0, 0);
}

// ---------------- prep kernels ----------------
__global__ void cvt_bf16(const float* __restrict__ src, u16* __restrict__ dst) {
  int t = blockIdx.x * 256 + threadIdx.x;
  float4v a = *(const float4v*)(src + (size_t)t * 8);
  float4v b = *(const float4v*)(src + (size_t)t * 8 + 4);
  short8 o;
#pragma unroll
  for (int j = 0; j < 4; ++j) o[j] = (short)f2bf(a[j]);
#pragma unroll
  for (int j = 0; j < 4; ++j) o[4 + j] = (short)f2bf(b[j]);
  *(short8*)(dst + (size_t)t * 8) = o;
}

// W_O [16,1024,64] f32 -> Wot[d, i*64+h] bf16
__global__ void prep_wo(const float* __restrict__ WO, u16* __restrict__ Wot) {
  int t = blockIdx.x * 256 + threadIdx.x;  // 0..131071
  int i = t >> 13;
  int d = (t >> 3) & 1023;
  int h0 = (t & 7) * 8;
  const float* src = WO + (size_t)i * 65536 + d * 64 + h0;
  float4v a = *(const float4v*)(src);
  float4v b = *(const float4v*)(src + 4);
  short8 o;
#pragma unroll
  for (int j = 0; j < 4; ++j) o[j] = (short)f2bf(a[j]);
#pragma unroll
  for (int j = 0; j < 4; ++j) o[4 + j] = (short)f2bf(b[j]);
  *(short8*)(Wot + (size_t)d * 1024 + i * 64 + h0) = o;
}

__global__ void prep_bqkv(const float* __restrict__ bQ, const float* __restrict__ bK,
                          const float* __restrict__ bV, float* __restrict__ bqkv) {
  int t = blockIdx.x * 256 + threadIdx.x;
  if (t < 3072)
    bqkv[t] = (t < 1024) ? bQ[t] : (t < 2048) ? bK[t - 1024] : bV[t - 2048];
}

// ---------------- layernorm (ln_pre): f32 in -> bf16 out ----------------
__global__ void ln_f32(const float* __restrict__ x, u16* __restrict__ y) {
  __shared__ float red1[4];
  __shared__ float red2[4];
  int token = blockIdx.x;
  int tid = threadIdx.x;
  int w = tid >> 6;
  const float* xr = x + (size_t)token * 1024;
  float4v v = *(const float4v*)(xr + tid * 4);
  float s = v[0] + v[1] + v[2] + v[3];
#pragma unroll
  for (int m = 32; m >= 1; m >>= 1) s += __shfl_xor(s, m);
  if ((tid & 63) == 0) red1[w] = s;
  __syncthreads();
  float mean = (red1[0] + red1[1] + red1[2] + red1[3]) * (1.0f / 1024.0f);
  float ss = 0.0f;
#pragma unroll
  for (int j = 0; j < 4; ++j) { v[j] -= mean; ss += v[j] * v[j]; }
#pragma unroll
  for (int m = 32; m >= 1; m >>= 1) ss += __shfl_xor(ss, m);
  if ((tid & 63) == 0) red2[w] = ss;
  __syncthreads();
  float ms = (red2[0] + red2[1] + red2[2] + red2[3]) * (1.0f / 1024.0f);
  float inv = 1.0f / sqrtf(ms + 1e-5f);
  ushort4v o;
#pragma unroll
  for (int j = 0; j < 4; ++j) o[j] = f2bf(v[j] * inv);
  *(ushort4v*)(y + (size_t)token * 1024 + tid * 4) = o;
}

// ---------------- GEMM: C[M,N] = A[M,K](bf16, stride lda) * Bw[N,K]^T ----------------
// VSPLIT: cols >= 2048 are written transposed to vTout[(col-2048)*4096 + row].
template <int BN, bool GELU, bool VSPLIT, typename TO, typename TR>
__global__ __launch_bounds__(256) void gemm_bt(
    const u16* __restrict__ A, const u16* __restrict__ Bw,
    const float* __restrict__ bias, const TR* __restrict__ resid,
    TO* __restrict__ C, u16* __restrict__ vTout, int M, int N, int K,
    int lda, int ldc) {
  constexpr int BM = 128, BK = 32;
  constexpr int FI = 4, FJ = BN / 32;
  constexpr int CA = BM * 4 / 256;
  constexpr int CB = BN * 4 / 256;
  __shared__ __align__(16) u16 As[BM * BK];
  __shared__ __align__(16) u16 Bs[BN * BK];
  const int tid = threadIdx.x;
  const int w = tid >> 6, lane = tid & 63;
  const int quad = lane >> 4, l16 = lane & 15;
  const int m0 = blockIdx.x * BM, n0 = blockIdx.y * BN;
  const int wm = (w >> 1) * 64, wn = (w & 1) * (BN / 2);
  float4v acc[FI][FJ] = {};
  for (int k0 = 0; k0 < K; k0 += BK) {
    __syncthreads();
#pragma unroll
    for (int t = 0; t < CA; ++t) {
      int chunk = (w * CA + t) * 64 + lane;
      int row = chunk >> 2, seg = chunk & 3;
      gload_lds16(A + (size_t)(m0 + row) * lda + k0 + seg * 8,
                  As + (w * CA + t) * 512);
    }
#pragma unroll
    for (int t = 0; t < CB; ++t) {
      int chunk = (w * CB + t) * 64 + lane;
      int row = chunk >> 2, seg = chunk & 3;
      gload_lds16(Bw + (size_t)(n0 + row) * K + k0 + seg * 8,
                  Bs + (w * CB + t) * 512);
    }
    __syncthreads();
    short8 a[FI], b[FJ];
#pragma unroll
    for (int fi = 0; fi < FI; ++fi)
      a[fi] = *(const short8*)(As + (wm + fi * 16 + l16) * BK + quad * 8);
#pragma unroll
    for (int fj = 0; fj < FJ; ++fj)
      b[fj] = *(const short8*)(Bs + (wn + fj * 16 + l16) * BK + quad * 8);
#pragma unroll
    for (int fi = 0; fi < FI; ++fi)
#pragma unroll
      for (int fj = 0; fj < FJ; ++fj)
        acc[fi][fj] = __builtin_amdgcn_mfma_f32_16x16x32_bf16(
            a[fi], b[fj], acc[fi][fj], 0, 0, 0);
  }
#pragma unroll
  for (int fi = 0; fi < FI; ++fi) {
#pragma unroll
    for (int fj = 0; fj < FJ; ++fj) {
      int col = n0 + wn + fj * 16 + l16;
      float bv = bias ? bias[col] : 0.0f;
#pragma unroll
      for (int r = 0; r < 4; ++r) {
        int row = m0 + wm + fi * 16 + quad * 4 + r;
        float val = acc[fi][fj][r] + bv;
        if (resid) val += ldres(resid + (size_t)row * N + col);
        if (GELU) val = gelu_new(val);
        if (VSPLIT && col >= 2048) {
          vTout[(size_t)(col - 2048) * 4096 + row] = f2bf(val);
        } else if constexpr (sizeof(TO) == 2) {
          C[(size_t)row * ldc + col] = f2bf(val);
        } else {
          C[(size_t)row * ldc + col] = val;
        }
      }
    }
  }
}

// ---------------- single-pass flash attention (causal, online softmax, exp2) ----------------
// qk: [B*S, 2048] (q|k); vT: [1024][4096] = V transposed. z -> q half of qk.
__global__ __launch_bounds__(256) void attn_flash(u16* __restrict__ qk,
                                                  const u16* __restrict__ vT) {
  constexpr int PADK = 72;
  constexpr float C2 = 0.18033688011112042f;  // (1/8) * log2(e)
  __shared__ __align__(16) u16 Ks[64 * PADK];
  __shared__ __align__(16) u16 Vt[64 * PADK];
  __shared__ __align__(16) u16 Ps[4][16 * PADK];
  const int qt = 31 - blockIdx.x;  // longest blocks first
  const int head = blockIdx.y, b = blockIdx.z;
  const int tid = threadIdx.x;
  const int w = tid >> 6, lane = tid & 63;
  const int quad = lane >> 4, l16 = lane & 15;
  const int q0 = qt * 64;
  const size_t tokB = (size_t)b * 2048;

  short8 aq[2];
#pragma unroll
  for (int ks = 0; ks < 2; ++ks)
    aq[ks] = *(const short8*)(qk + (tokB + q0 + w * 16 + l16) * 2048 +
                              head * 64 + ks * 32 + quad * 8);

  const u16* kbase = qk + tokB * 2048 + 1024 + head * 64;   // + (kk0+row)*2048 + seg*8
  const u16* vbase = vT + (size_t)head * 64 * 4096 + tokB;  // + row*4096 + kk0 + seg*8

  float m_st[4] = {-1e30f, -1e30f, -1e30f, -1e30f};
  float l_st[4] = {0.f, 0.f, 0.f, 0.f};
  float4v o_acc[4] = {};

  for (int kt = 0; kt <= qt; ++kt) {
    const int kk0 = kt * 64;
    __syncthreads();
#pragma unroll
    for (int i = 0; i < 2; ++i) {
      int flat = tid * 2 + i;  // 0..511
      int row = flat >> 3, seg = flat & 7;
      *(short8*)(Ks + row * PADK + seg * 8) =
          *(const short8*)(kbase + (size_t)(kk0 + row) * 2048 + seg * 8);
      *(short8*)(Vt + row * PADK + seg * 8) =
          *(const short8*)(vbase + (size_t)row * 4096 + kk0 + seg * 8);
    }
    __syncthreads();

    float4v s[4];
#pragma unroll
    for (int fj = 0; fj < 4; ++fj) {
      float4v t = {0.f, 0.f, 0.f, 0.f};
#pragma unroll
      for (int ks = 0; ks < 2; ++ks) {
        short8 bk = *(const short8*)(Ks + (fj * 16 + l16) * PADK + ks * 32 + quad * 8);
        t = __builtin_amdgcn_mfma_f32_16x16x32_bf16(aq[ks], bk, t, 0, 0, 0);
      }
      s[fj] = t;
    }
#pragma unroll
    for (int fj = 0; fj < 4; ++fj)
#pragma unroll
      for (int r = 0; r < 4; ++r) s[fj][r] *= C2;
    if (kt == qt) {
#pragma unroll
      for (int fj = 0; fj < 4; ++fj) {
        int col = kk0 + fj * 16 + l16;
#pragma unroll
        for (int r = 0; r < 4; ++r) {
          int row = q0 + w * 16 + quad * 4 + r;
          if (col > row) s[fj][r] = -1e30f;
        }
      }
    }
    float mx[4];
#pragma unroll
    for (int r = 0; r < 4; ++r) {
      float m = s[0][r];
#pragma unroll
      for (int fj = 1; fj < 4; ++fj) m = fmaxf(m, s[fj][r]);
      m = fmaxf(m, __shfl_xor(m, 1));
      m = fmaxf(m, __shfl_xor(m, 2));
      m = fmaxf(m, __shfl_xor(m, 4));
      m = fmaxf(m, __shfl_xor(m, 8));
      mx[r] = m;
    }
    float alpha[4];
#pragma unroll
    for (int r = 0; r < 4; ++r) {
      float mnew = fmaxf(m_st[r], mx[r]);
      alpha[r] = __builtin_amdgcn_exp2f(m_st[r] - mnew);
      m_st[r] = mnew;
    }
    float rs[4] = {0.f, 0.f, 0.f, 0.f};
#pragma unroll
    for (int fj = 0; fj < 4; ++fj)
#pragma unroll
      for (int r = 0; r < 4; ++r) {
        float pv = __builtin_amdgcn_exp2f(s[fj][r] - m_st[r]);
        s[fj][r] = pv;
        rs[r] += pv;
      }
#pragma unroll
    for (int r = 0; r < 4; ++r) {
      float t = rs[r];
      t += __shfl_xor(t, 1);
      t += __shfl_xor(t, 2);
      t += __shfl_xor(t, 4);
      t += __shfl_xor(t, 8);
      l_st[r] = l_st[r] * alpha[r] + t;
    }
#pragma unroll
    for (int fj = 0; fj < 4; ++fj)
#pragma unroll
      for (int r = 0; r < 4; ++r) o_acc[fj][r] *= alpha[r];
#pragma unroll
    for (int fj = 0; fj < 4; ++fj)
#pragma unroll
      for (int r = 0; r < 4; ++r)
        Ps[w][(quad * 4 + r) * PADK + fj * 16 + l16] = f2bf(s[fj][r]);
    short8 ap[2];
#pragma unroll
    for (int ks = 0; ks < 2; ++ks)
      ap[ks] = *(const short8*)(&Ps[w][l16 * PADK + ks * 32 + quad * 8]);
#pragma unroll
    for (int fj = 0; fj < 4; ++fj)
#pragma unroll
      for (int ks = 0; ks < 2; ++ks) {
        short8 bv = *(const short8*)(Vt + (fj * 16 + l16) * PADK + ks * 32 + quad * 8);
        o_acc[fj] = __builtin_amdgcn_mfma_f32_16x16x32_bf16(ap[ks], bv, o_acc[fj], 0, 0, 0);
      }
  }
#pragma unroll
  for (int r = 0; r < 4; ++r) {
    float inv = 1.0f / l_st[r];
    int row = q0 + w * 16 + quad * 4 + r;
#pragma unroll
    for (int fj = 0; fj < 4; ++fj)
      qk[(tokB + row) * 2048 + head * 64 + fj * 16 + l16] =
          f2bf(o_acc[fj][r] * inv);
  }
}

// ---------------- launcher ----------------
extern "C" void kernel_launch(void* const* d_in, const int* in_sizes, int n_in,
                              void* d_out, int out_size, void* d_ws, size_t ws_size,
                              hipStream_t stream) {
  const float* x = (const float*)d_in[0];
  const float* W_Q = (const float*)d_in[1];
  const float* W_K = (const float*)d_in[2];
  const float* W_V = (const float*)d_in[3];
  const float* W_O = (const float*)d_in[4];
  const float* b_Q = (const float*)d_in[5];
  const float* b_K = (const float*)d_in[6];
  const float* b_V = (const float*)d_in[7];
  const float* b_O = (const float*)d_in[8];
  const float* W_in = (const float*)d_in[9];
  const float* b_in = (const float*)d_in[10];
  const float* W_out = (const float*)d_in[11];
  const float* b_out = (const float*)d_in[12];
  float* out = (float*)d_out;

  char* ws = (char*)d_ws;
  u16* Wqkv = (u16*)(ws);                 // [0, 6291456)
  u16* Wot  = (u16*)(ws + 6291456);       // [6291456, 8388608)
  u16* Wib  = (u16*)(ws + 8388608);       // [8388608, 16777216)
  u16* Wob  = (u16*)(ws + 16777216);      // [16777216, 25165824)
  float* bqkv = (float*)(ws + 25165824);  // [25165824, 25178112)
  u16* xn   = (u16*)(ws + 25178112);      // [25178112, 33566720)
  u16* qk   = (u16*)(ws + 33566720);      // [33566720, 50343936)  4096*2048 bf16
  u16* vT   = (u16*)(ws + 50343936);      // [50343936, 58732544)  1024*4096 bf16
  u16* hbuf = (u16*)(ws + 33566720);      // overlays qk+vT, 4096*4096, ends 67121152
  float* rm = (float*)(ws + 67121152);    // [67121152, 83898368)

  cvt_bf16<<<512, 256, 0, stream>>>(W_Q, Wqkv);
  cvt_bf16<<<512, 256, 0, stream>>>(W_K, Wqkv + 1048576);
  cvt_bf16<<<512, 256, 0, stream>>>(W_V, Wqkv + 2097152);
  cvt_bf16<<<2048, 256, 0, stream>>>(W_in, Wib);
  cvt_bf16<<<2048, 256, 0, stream>>>(W_out, Wob);
  prep_wo<<<512, 256, 0, stream>>>(W_O, Wot);
  prep_bqkv<<<12, 256, 0, stream>>>(b_Q, b_K, b_V, bqkv);

  ln_f32<<<4096, 256, 0, stream>>>(x, xn);
  // QKV: Q,K -> qk[4096][2048]; V -> vT[1024][4096] (transposed in epilogue)
  gemm_bt<128, false, true, u16, float><<<dim3(32, 24), 256, 0, stream>>>(
      xn, Wqkv, bqkv, (const float*)nullptr, qk, vT, 4096, 3072, 1024, 1024, 2048);
  attn_flash<<<dim3(32, 16, 2), 256, 0, stream>>>(qk, vT);
  // attn-out: BN=128 (was 64)
  gemm_bt<128, false, false, float, float><<<dim3(32, 8), 256, 0, stream>>>(
      qk /*z in q half, lda=2048*/, Wot, b_O, x, rm, nullptr, 4096, 1024, 1024, 2048, 1024);
  ln_f32<<<4096, 256, 0, stream>>>(rm, xn);
  gemm_bt<128, true, false, u16, float><<<dim3(32, 32), 256, 0, stream>>>(
      xn, Wib, b_in, (const float*)nullptr, hbuf, nullptr, 4096, 4096, 1024, 1024, 4096);
  // MLP-out: BN=128 (was 64)
  gemm_bt<128, false, false, float, float><<<dim3(32, 8), 256, 0, stream>>>(
      hbuf, Wob, b_out, rm, out, nullptr, 4096, 1024, 4096, 4096, 1024);
}

// Round 9
// 441.911 us; speedup vs baseline: 1.2268x; 1.2268x over previous
//
#include <hip/hip_runtime.h>

typedef unsigned short u16;
typedef __attribute__((ext_vector_type(8))) short short8;
typedef __attribute__((ext_vector_type(4))) unsigned short ushort4v;
typedef __attribute__((ext_vector_type(4))) float float4v;

__device__ __forceinline__ float bf2f(u16 u) {
  union { unsigned int i; float f; } c; c.i = ((unsigned int)u) << 16; return c.f;
}
__device__ __forceinline__ u16 f2bf(float f) {
  union { float f; unsigned int i; } c; c.f = f;
  unsigned int u = c.i;
  return (u16)((u + 0x7fffu + ((u >> 16) & 1u)) >> 16);
}
__device__ __forceinline__ float gelu_new(float x) {
  const float c = 0.7978845608028654f;
  float t = tanhf(c * (x + 0.044715f * x * x * x));
  return 0.5f * x * (1.0f + t);
}
__device__ __forceinline__ float ldres(const float* p) { return *p; }
__device__ __forceinline__ float ldres(const u16* p) { return bf2f(*p); }

__device__ __forceinline__ void gload_lds16(const u16* g, u16* l) {
  __builtin_amdgcn_global_load_lds(
      (const __attribute__((address_space(1))) unsigned int*)g,
      (__attribute__((address_space(3))) unsigned int*)l, 16, 0, 0);
}

// ---------------- prep kernels ----------------
__global__ void cvt_bf16(const float* __restrict__ src, u16* __restrict__ dst) {
  int t = blockIdx.x * 256 + threadIdx.x;
  float4v a = *(const float4v*)(src + (size_t)t * 8);
  float4v b = *(const float4v*)(src + (size_t)t * 8 + 4);
  short8 o;
#pragma unroll
  for (int j = 0; j < 4; ++j) o[j] = (short)f2bf(a[j]);
#pragma unroll
  for (int j = 0; j < 4; ++j) o[4 + j] = (short)f2bf(b[j]);
  *(short8*)(dst + (size_t)t * 8) = o;
}

// W_O [16,1024,64] f32 -> Wot[d, i*64+h] bf16
__global__ void prep_wo(const float* __restrict__ WO, u16* __restrict__ Wot) {
  int t = blockIdx.x * 256 + threadIdx.x;  // 0..131071
  int i = t >> 13;
  int d = (t >> 3) & 1023;
  int h0 = (t & 7) * 8;
  const float* src = WO + (size_t)i * 65536 + d * 64 + h0;
  float4v a = *(const float4v*)(src);
  float4v b = *(const float4v*)(src + 4);
  short8 o;
#pragma unroll
  for (int j = 0; j < 4; ++j) o[j] = (short)f2bf(a[j]);
#pragma unroll
  for (int j = 0; j < 4; ++j) o[4 + j] = (short)f2bf(b[j]);
  *(short8*)(Wot + (size_t)d * 1024 + i * 64 + h0) = o;
}

__global__ void prep_bqkv(const float* __restrict__ bQ, const float* __restrict__ bK,
                          const float* __restrict__ bV, float* __restrict__ bqkv) {
  int t = blockIdx.x * 256 + threadIdx.x;
  if (t < 3072)
    bqkv[t] = (t < 1024) ? bQ[t] : (t < 2048) ? bK[t - 1024] : bV[t - 2048];
}

// ---------------- layernorm (ln_pre): f32 in -> bf16 out ----------------
__global__ void ln_f32(const float* __restrict__ x, u16* __restrict__ y) {
  __shared__ float red1[4];
  __shared__ float red2[4];
  int token = blockIdx.x;
  int tid = threadIdx.x;
  int w = tid >> 6;
  const float* xr = x + (size_t)token * 1024;
  float4v v = *(const float4v*)(xr + tid * 4);
  float s = v[0] + v[1] + v[2] + v[3];
#pragma unroll
  for (int m = 32; m >= 1; m >>= 1) s += __shfl_xor(s, m);
  if ((tid & 63) == 0) red1[w] = s;
  __syncthreads();
  float mean = (red1[0] + red1[1] + red1[2] + red1[3]) * (1.0f / 1024.0f);
  float ss = 0.0f;
#pragma unroll
  for (int j = 0; j < 4; ++j) { v[j] -= mean; ss += v[j] * v[j]; }
#pragma unroll
  for (int m = 32; m >= 1; m >>= 1) ss += __shfl_xor(ss, m);
  if ((tid & 63) == 0) red2[w] = ss;
  __syncthreads();
  float ms = (red2[0] + red2[1] + red2[2] + red2[3]) * (1.0f / 1024.0f);
  float inv = 1.0f / sqrtf(ms + 1e-5f);
  ushort4v o;
#pragma unroll
  for (int j = 0; j < 4; ++j) o[j] = f2bf(v[j] * inv);
  *(ushort4v*)(y + (size_t)token * 1024 + tid * 4) = o;
}

// ---------------- GEMM: C[M,N] = A[M,K](bf16, stride lda) * Bw[N,K]^T ----------------
// VSPLIT: cols >= 2048 are written transposed to vTout[(col-2048)*4096 + row].
template <int BN, bool GELU, bool VSPLIT, typename TO, typename TR>
__global__ __launch_bounds__(256) void gemm_bt(
    const u16* __restrict__ A, const u16* __restrict__ Bw,
    const float* __restrict__ bias, const TR* __restrict__ resid,
    TO* __restrict__ C, u16* __restrict__ vTout, int M, int N, int K,
    int lda, int ldc) {
  constexpr int BM = 128, BK = 32;
  constexpr int FI = 4, FJ = BN / 32;
  constexpr int CA = BM * 4 / 256;
  constexpr int CB = BN * 4 / 256;
  __shared__ __align__(16) u16 As[BM * BK];
  __shared__ __align__(16) u16 Bs[BN * BK];
  const int tid = threadIdx.x;
  const int w = tid >> 6, lane = tid & 63;
  const int quad = lane >> 4, l16 = lane & 15;
  const int m0 = blockIdx.x * BM, n0 = blockIdx.y * BN;
  const int wm = (w >> 1) * 64, wn = (w & 1) * (BN / 2);
  float4v acc[FI][FJ] = {};
  for (int k0 = 0; k0 < K; k0 += BK) {
    __syncthreads();
#pragma unroll
    for (int t = 0; t < CA; ++t) {
      int chunk = (w * CA + t) * 64 + lane;
      int row = chunk >> 2, seg = chunk & 3;
      gload_lds16(A + (size_t)(m0 + row) * lda + k0 + seg * 8,
                  As + (w * CA + t) * 512);
    }
#pragma unroll
    for (int t = 0; t < CB; ++t) {
      int chunk = (w * CB + t) * 64 + lane;
      int row = chunk >> 2, seg = chunk & 3;
      gload_lds16(Bw + (size_t)(n0 + row) * K + k0 + seg * 8,
                  Bs + (w * CB + t) * 512);
    }
    __syncthreads();
    short8 a[FI], b[FJ];
#pragma unroll
    for (int fi = 0; fi < FI; ++fi)
      a[fi] = *(const short8*)(As + (wm + fi * 16 + l16) * BK + quad * 8);
#pragma unroll
    for (int fj = 0; fj < FJ; ++fj)
      b[fj] = *(const short8*)(Bs + (wn + fj * 16 + l16) * BK + quad * 8);
#pragma unroll
    for (int fi = 0; fi < FI; ++fi)
#pragma unroll
      for (int fj = 0; fj < FJ; ++fj)
        acc[fi][fj] = __builtin_amdgcn_mfma_f32_16x16x32_bf16(
            a[fi], b[fj], acc[fi][fj], 0, 0, 0);
  }
#pragma unroll
  for (int fi = 0; fi < FI; ++fi) {
#pragma unroll
    for (int fj = 0; fj < FJ; ++fj) {
      int col = n0 + wn + fj * 16 + l16;
      float bv = bias ? bias[col] : 0.0f;
#pragma unroll
      for (int r = 0; r < 4; ++r) {
        int row = m0 + wm + fi * 16 + quad * 4 + r;
        float val = acc[fi][fj][r] + bv;
        if (resid) val += ldres(resid + (size_t)row * N + col);
        if (GELU) val = gelu_new(val);
        if (VSPLIT && col >= 2048) {
          vTout[(size_t)(col - 2048) * 4096 + row] = f2bf(val);
        } else if constexpr (sizeof(TO) == 2) {
          C[(size_t)row * ldc + col] = f2bf(val);
        } else {
          C[(size_t)row * ldc + col] = val;
        }
      }
    }
  }
}

// ---------------- single-pass flash attention (causal, online softmax, exp2) ----------------
// qk: [B*S, 2048] (q|k); vT: [1024][4096] = V transposed. z -> q half of qk.
// Grid: 1024 linear blocks; id = qtile_rev*32 + (head*2+b) so that id%8 groups
// all q-tiles of one (b,h) on one XCD (K/V stays in that XCD's 4MB L2).
__global__ __launch_bounds__(256) void attn_flash(u16* __restrict__ qk,
                                                  const u16* __restrict__ vT) {
  constexpr int PADK = 72;
  constexpr float C2 = 0.18033688011112042f;  // (1/8) * log2(e)
  __shared__ __align__(16) u16 Ks[64 * PADK];
  __shared__ __align__(16) u16 Vt[64 * PADK];
  __shared__ __align__(16) u16 Ps[4][16 * PADK];
  const int id = blockIdx.x;
  const int qt = 31 - (id >> 5);  // longest blocks first
  const int combo = id & 31;
  const int head = combo >> 1, b = combo & 1;
  const int tid = threadIdx.x;
  const int w = tid >> 6, lane = tid & 63;
  const int quad = lane >> 4, l16 = lane & 15;
  const int q0 = qt * 64;
  const size_t tokB = (size_t)b * 2048;

  short8 aq[2];
#pragma unroll
  for (int ks = 0; ks < 2; ++ks)
    aq[ks] = *(const short8*)(qk + (tokB + q0 + w * 16 + l16) * 2048 +
                              head * 64 + ks * 32 + quad * 8);

  const u16* kbase = qk + tokB * 2048 + 1024 + head * 64;   // + (kk0+row)*2048 + seg*8
  const u16* vbase = vT + (size_t)head * 64 * 4096 + tokB;  // + row*4096 + kk0 + seg*8

  float m_st[4] = {-1e30f, -1e30f, -1e30f, -1e30f};
  float l_st[4] = {0.f, 0.f, 0.f, 0.f};
  float4v o_acc[4] = {};

  for (int kt = 0; kt <= qt; ++kt) {
    const int kk0 = kt * 64;
    __syncthreads();
#pragma unroll
    for (int i = 0; i < 2; ++i) {
      int flat = tid * 2 + i;  // 0..511
      int row = flat >> 3, seg = flat & 7;
      *(short8*)(Ks + row * PADK + seg * 8) =
          *(const short8*)(kbase + (size_t)(kk0 + row) * 2048 + seg * 8);
      *(short8*)(Vt + row * PADK + seg * 8) =
          *(const short8*)(vbase + (size_t)row * 4096 + kk0 + seg * 8);
    }
    __syncthreads();

    float4v s[4];
#pragma unroll
    for (int fj = 0; fj < 4; ++fj) {
      float4v t = {0.f, 0.f, 0.f, 0.f};
#pragma unroll
      for (int ks = 0; ks < 2; ++ks) {
        short8 bk = *(const short8*)(Ks + (fj * 16 + l16) * PADK + ks * 32 + quad * 8);
        t = __builtin_amdgcn_mfma_f32_16x16x32_bf16(aq[ks], bk, t, 0, 0, 0);
      }
      s[fj] = t;
    }
#pragma unroll
    for (int fj = 0; fj < 4; ++fj)
#pragma unroll
      for (int r = 0; r < 4; ++r) s[fj][r] *= C2;
    if (kt == qt) {
#pragma unroll
      for (int fj = 0; fj < 4; ++fj) {
        int col = kk0 + fj * 16 + l16;
#pragma unroll
        for (int r = 0; r < 4; ++r) {
          int row = q0 + w * 16 + quad * 4 + r;
          if (col > row) s[fj][r] = -1e30f;
        }
      }
    }
    float mx[4];
#pragma unroll
    for (int r = 0; r < 4; ++r) {
      float m = s[0][r];
#pragma unroll
      for (int fj = 1; fj < 4; ++fj) m = fmaxf(m, s[fj][r]);
      m = fmaxf(m, __shfl_xor(m, 1));
      m = fmaxf(m, __shfl_xor(m, 2));
      m = fmaxf(m, __shfl_xor(m, 4));
      m = fmaxf(m, __shfl_xor(m, 8));
      mx[r] = m;
    }
    float alpha[4];
#pragma unroll
    for (int r = 0; r < 4; ++r) {
      float mnew = fmaxf(m_st[r], mx[r]);
      alpha[r] = __builtin_amdgcn_exp2f(m_st[r] - mnew);
      m_st[r] = mnew;
    }
    float rs[4] = {0.f, 0.f, 0.f, 0.f};
#pragma unroll
    for (int fj = 0; fj < 4; ++fj)
#pragma unroll
      for (int r = 0; r < 4; ++r) {
        float pv = __builtin_amdgcn_exp2f(s[fj][r] - m_st[r]);
        s[fj][r] = pv;
        rs[r] += pv;
      }
#pragma unroll
    for (int r = 0; r < 4; ++r) {
      float t = rs[r];
      t += __shfl_xor(t, 1);
      t += __shfl_xor(t, 2);
      t += __shfl_xor(t, 4);
      t += __shfl_xor(t, 8);
      l_st[r] = l_st[r] * alpha[r] + t;
    }
#pragma unroll
    for (int fj = 0; fj < 4; ++fj)
#pragma unroll
      for (int r = 0; r < 4; ++r) o_acc[fj][r] *= alpha[r];
#pragma unroll
    for (int fj = 0; fj < 4; ++fj)
#pragma unroll
      for (int r = 0; r < 4; ++r)
        Ps[w][(quad * 4 + r) * PADK + fj * 16 + l16] = f2bf(s[fj][r]);
    short8 ap[2];
#pragma unroll
    for (int ks = 0; ks < 2; ++ks)
      ap[ks] = *(const short8*)(&Ps[w][l16 * PADK + ks * 32 + quad * 8]);
#pragma unroll
    for (int fj = 0; fj < 4; ++fj)
#pragma unroll
      for (int ks = 0; ks < 2; ++ks) {
        short8 bv = *(const short8*)(Vt + (fj * 16 + l16) * PADK + ks * 32 + quad * 8);
        o_acc[fj] = __builtin_amdgcn_mfma_f32_16x16x32_bf16(ap[ks], bv, o_acc[fj], 0, 0, 0);
      }
  }
#pragma unroll
  for (int r = 0; r < 4; ++r) {
    float inv = 1.0f / l_st[r];
    int row = q0 + w * 16 + quad * 4 + r;
#pragma unroll
    for (int fj = 0; fj < 4; ++fj)
      qk[(tokB + row) * 2048 + head * 64 + fj * 16 + l16] =
          f2bf(o_acc[fj][r] * inv);
  }
}

// ---------------- launcher ----------------
extern "C" void kernel_launch(void* const* d_in, const int* in_sizes, int n_in,
                              void* d_out, int out_size, void* d_ws, size_t ws_size,
                              hipStream_t stream) {
  const float* x = (const float*)d_in[0];
  const float* W_Q = (const float*)d_in[1];
  const float* W_K = (const float*)d_in[2];
  const float* W_V = (const float*)d_in[3];
  const float* W_O = (const float*)d_in[4];
  const float* b_Q = (const float*)d_in[5];
  const float* b_K = (const float*)d_in[6];
  const float* b_V = (const float*)d_in[7];
  const float* b_O = (const float*)d_in[8];
  const float* W_in = (const float*)d_in[9];
  const float* b_in = (const float*)d_in[10];
  const float* W_out = (const float*)d_in[11];
  const float* b_out = (const float*)d_in[12];
  float* out = (float*)d_out;

  char* ws = (char*)d_ws;
  u16* Wqkv = (u16*)(ws);                 // [0, 6291456)
  u16* Wot  = (u16*)(ws + 6291456);       // [6291456, 8388608)
  u16* Wib  = (u16*)(ws + 8388608);       // [8388608, 16777216)
  u16* Wob  = (u16*)(ws + 16777216);      // [16777216, 25165824)
  float* bqkv = (float*)(ws + 25165824);  // [25165824, 25178112)
  u16* xn   = (u16*)(ws + 25178112);      // [25178112, 33566720)
  u16* qk   = (u16*)(ws + 33566720);      // [33566720, 50343936)  4096*2048 bf16
  u16* vT   = (u16*)(ws + 50343936);      // [50343936, 58732544)  1024*4096 bf16
  u16* hbuf = (u16*)(ws + 33566720);      // overlays qk+vT, 4096*4096, ends 67121152
  float* rm = (float*)(ws + 67121152);    // [67121152, 83898368)

  cvt_bf16<<<512, 256, 0, stream>>>(W_Q, Wqkv);
  cvt_bf16<<<512, 256, 0, stream>>>(W_K, Wqkv + 1048576);
  cvt_bf16<<<512, 256, 0, stream>>>(W_V, Wqkv + 2097152);
  cvt_bf16<<<2048, 256, 0, stream>>>(W_in, Wib);
  cvt_bf16<<<2048, 256, 0, stream>>>(W_out, Wob);
  prep_wo<<<512, 256, 0, stream>>>(W_O, Wot);
  prep_bqkv<<<12, 256, 0, stream>>>(b_Q, b_K, b_V, bqkv);

  ln_f32<<<4096, 256, 0, stream>>>(x, xn);
  // QKV: Q,K -> qk[4096][2048]; V -> vT[1024][4096] (transposed in epilogue)
  gemm_bt<128, false, true, u16, float><<<dim3(32, 24), 256, 0, stream>>>(
      xn, Wqkv, bqkv, (const float*)nullptr, qk, vT, 4096, 3072, 1024, 1024, 2048);
  attn_flash<<<1024, 256, 0, stream>>>(qk, vT);
  // attn-out: BN=64 (revert)
  gemm_bt<64, false, false, float, float><<<dim3(32, 16), 256, 0, stream>>>(
      qk /*z in q half, lda=2048*/, Wot, b_O, x, rm, nullptr, 4096, 1024, 1024, 2048, 1024);
  ln_f32<<<4096, 256, 0, stream>>>(rm, xn);
  gemm_bt<128, true, false, u16, float><<<dim3(32, 32), 256, 0, stream>>>(
      xn, Wib, b_in, (const float*)nullptr, hbuf, nullptr, 4096, 4096, 1024, 1024, 4096);
  // MLP-out: BN=64 (revert)
  gemm_bt<64, false, false, float, float><<<dim3(32, 16), 256, 0, stream>>>(
      hbuf, Wob, b_out, rm, out, nullptr, 4096, 1024, 4096, 4096, 1024);
}

// Round 10
// 421.255 us; speedup vs baseline: 1.2870x; 1.0490x over previous
//
#include <hip/hip_runtime.h>

typedef unsigned short u16;
typedef __attribute__((ext_vector_type(8))) short short8;
typedef __attribute__((ext_vector_type(4))) unsigned short ushort4v;
typedef __attribute__((ext_vector_type(4))) float float4v;

__device__ __forceinline__ float bf2f(u16 u) {
  union { unsigned int i; float f; } c; c.i = ((unsigned int)u) << 16; return c.f;
}
__device__ __forceinline__ u16 f2bf(float f) {
  union { float f; unsigned int i; } c; c.f = f;
  unsigned int u = c.i;
  return (u16)((u + 0x7fffu + ((u >> 16) & 1u)) >> 16);
}
// 0.5x(1+tanh(c(x+0.044715x^3))) == x * sigmoid(2c(x+0.044715x^3))
//   == x / (1 + exp2(-(k1*x + k3*x^3))), k1 = 2c*log2(e), k3 = k1*0.044715
__device__ __forceinline__ float gelu_new(float x) {
  const float k1 = 2.30218776f;
  const float k3 = 0.10294233f;
  float x3 = x * x * x;
  float e = __builtin_amdgcn_exp2f(-(k1 * x + k3 * x3));
  return x / (1.0f + e);
}
__device__ __forceinline__ float ldres(const float* p) { return *p; }
__device__ __forceinline__ float ldres(const u16* p) { return bf2f(*p); }

__device__ __forceinline__ void gload_lds16(const u16* g, u16* l) {
  __builtin_amdgcn_global_load_lds(
      (const __attribute__((address_space(1))) unsigned int*)g,
      (__attribute__((address_space(3))) unsigned int*)l, 16, 0, 0);
}

// ---------------- prep kernels ----------------
__global__ void cvt_bf16(const float* __restrict__ src, u16* __restrict__ dst) {
  int t = blockIdx.x * 256 + threadIdx.x;
  float4v a = *(const float4v*)(src + (size_t)t * 8);
  float4v b = *(const float4v*)(src + (size_t)t * 8 + 4);
  short8 o;
#pragma unroll
  for (int j = 0; j < 4; ++j) o[j] = (short)f2bf(a[j]);
#pragma unroll
  for (int j = 0; j < 4; ++j) o[4 + j] = (short)f2bf(b[j]);
  *(short8*)(dst + (size_t)t * 8) = o;
}

// W_O [16,1024,64] f32 -> Wot[d, i*64+h] bf16
__global__ void prep_wo(const float* __restrict__ WO, u16* __restrict__ Wot) {
  int t = blockIdx.x * 256 + threadIdx.x;  // 0..131071
  int i = t >> 13;
  int d = (t >> 3) & 1023;
  int h0 = (t & 7) * 8;
  const float* src = WO + (size_t)i * 65536 + d * 64 + h0;
  float4v a = *(const float4v*)(src);
  float4v b = *(const float4v*)(src + 4);
  short8 o;
#pragma unroll
  for (int j = 0; j < 4; ++j) o[j] = (short)f2bf(a[j]);
#pragma unroll
  for (int j = 0; j < 4; ++j) o[4 + j] = (short)f2bf(b[j]);
  *(short8*)(Wot + (size_t)d * 1024 + i * 64 + h0) = o;
}

__global__ void prep_bqkv(const float* __restrict__ bQ, const float* __restrict__ bK,
                          const float* __restrict__ bV, float* __restrict__ bqkv) {
  int t = blockIdx.x * 256 + threadIdx.x;
  if (t < 3072)
    bqkv[t] = (t < 1024) ? bQ[t] : (t < 2048) ? bK[t - 1024] : bV[t - 2048];
}

// ---------------- layernorm (ln_pre): f32 in -> bf16 out ----------------
__global__ void ln_f32(const float* __restrict__ x, u16* __restrict__ y) {
  __shared__ float red1[4];
  __shared__ float red2[4];
  int token = blockIdx.x;
  int tid = threadIdx.x;
  int w = tid >> 6;
  const float* xr = x + (size_t)token * 1024;
  float4v v = *(const float4v*)(xr + tid * 4);
  float s = v[0] + v[1] + v[2] + v[3];
#pragma unroll
  for (int m = 32; m >= 1; m >>= 1) s += __shfl_xor(s, m);
  if ((tid & 63) == 0) red1[w] = s;
  __syncthreads();
  float mean = (red1[0] + red1[1] + red1[2] + red1[3]) * (1.0f / 1024.0f);
  float ss = 0.0f;
#pragma unroll
  for (int j = 0; j < 4; ++j) { v[j] -= mean; ss += v[j] * v[j]; }
#pragma unroll
  for (int m = 32; m >= 1; m >>= 1) ss += __shfl_xor(ss, m);
  if ((tid & 63) == 0) red2[w] = ss;
  __syncthreads();
  float ms = (red2[0] + red2[1] + red2[2] + red2[3]) * (1.0f / 1024.0f);
  float inv = 1.0f / sqrtf(ms + 1e-5f);
  ushort4v o;
#pragma unroll
  for (int j = 0; j < 4; ++j) o[j] = f2bf(v[j] * inv);
  *(ushort4v*)(y + (size_t)token * 1024 + tid * 4) = o;
}

// ---------------- GEMM: C[M,N] = A[M,K](bf16, stride lda) * Bw[N,K]^T ----------------
// VSPLIT: cols >= 2048 are written transposed to vTout[(col-2048)*4096 + row].
template <int BN, int BK, bool GELU, bool VSPLIT, typename TO, typename TR>
__global__ __launch_bounds__(256) void gemm_bt(
    const u16* __restrict__ A, const u16* __restrict__ Bw,
    const float* __restrict__ bias, const TR* __restrict__ resid,
    TO* __restrict__ C, u16* __restrict__ vTout, int M, int N, int K,
    int lda, int ldc) {
  constexpr int BM = 128;
  constexpr int SEGS = BK / 8;           // 16B chunks per tile row
  constexpr int FI = 4, FJ = BN / 32;
  constexpr int CA = BM * SEGS / 256;    // chunks per thread (A tile)
  constexpr int CB = BN * SEGS / 256;
  __shared__ __align__(16) u16 As[BM * BK];
  __shared__ __align__(16) u16 Bs[BN * BK];
  const int tid = threadIdx.x;
  const int w = tid >> 6, lane = tid & 63;
  const int quad = lane >> 4, l16 = lane & 15;
  const int m0 = blockIdx.x * BM, n0 = blockIdx.y * BN;
  const int wm = (w >> 1) * 64, wn = (w & 1) * (BN / 2);
  float4v acc[FI][FJ] = {};
  for (int k0 = 0; k0 < K; k0 += BK) {
    __syncthreads();
#pragma unroll
    for (int t = 0; t < CA; ++t) {
      int chunk = (w * CA + t) * 64 + lane;
      int row = chunk / SEGS, seg = chunk % SEGS;
      gload_lds16(A + (size_t)(m0 + row) * lda + k0 + seg * 8,
                  As + (w * CA + t) * 512);
    }
#pragma unroll
    for (int t = 0; t < CB; ++t) {
      int chunk = (w * CB + t) * 64 + lane;
      int row = chunk / SEGS, seg = chunk % SEGS;
      gload_lds16(Bw + (size_t)(n0 + row) * K + k0 + seg * 8,
                  Bs + (w * CB + t) * 512);
    }
    __syncthreads();
#pragma unroll
    for (int kk = 0; kk < BK; kk += 32) {
      short8 a[FI], b[FJ];
#pragma unroll
      for (int fi = 0; fi < FI; ++fi)
        a[fi] = *(const short8*)(As + (wm + fi * 16 + l16) * BK + kk + quad * 8);
#pragma unroll
      for (int fj = 0; fj < FJ; ++fj)
        b[fj] = *(const short8*)(Bs + (wn + fj * 16 + l16) * BK + kk + quad * 8);
#pragma unroll
      for (int fi = 0; fi < FI; ++fi)
#pragma unroll
        for (int fj = 0; fj < FJ; ++fj)
          acc[fi][fj] = __builtin_amdgcn_mfma_f32_16x16x32_bf16(
              a[fi], b[fj], acc[fi][fj], 0, 0, 0);
    }
  }
#pragma unroll
  for (int fi = 0; fi < FI; ++fi) {
#pragma unroll
    for (int fj = 0; fj < FJ; ++fj) {
      int col = n0 + wn + fj * 16 + l16;
      float bv = bias ? bias[col] : 0.0f;
#pragma unroll
      for (int r = 0; r < 4; ++r) {
        int row = m0 + wm + fi * 16 + quad * 4 + r;
        float val = acc[fi][fj][r] + bv;
        if (resid) val += ldres(resid + (size_t)row * N + col);
        if (GELU) val = gelu_new(val);
        if (VSPLIT && col >= 2048) {
          vTout[(size_t)(col - 2048) * 4096 + row] = f2bf(val);
        } else if constexpr (sizeof(TO) == 2) {
          C[(size_t)row * ldc + col] = f2bf(val);
        } else {
          C[(size_t)row * ldc + col] = val;
        }
      }
    }
  }
}

// ---------------- single-pass flash attention (causal, online softmax, exp2) ----------------
// qk: [B*S, 2048] (q|k); vT: [1024][4096] = V transposed. z -> q half of qk.
// Grid: 1024 linear blocks; id = qtile_rev*32 + (head*2+b) so that id%8 groups
// all q-tiles of one (b,h) on one XCD (K/V stays in that XCD's 4MB L2).
__global__ __launch_bounds__(256) void attn_flash(u16* __restrict__ qk,
                                                  const u16* __restrict__ vT) {
  constexpr int PADK = 72;
  constexpr float C2 = 0.18033688011112042f;  // (1/8) * log2(e)
  __shared__ __align__(16) u16 Ks[64 * PADK];
  __shared__ __align__(16) u16 Vt[64 * PADK];
  __shared__ __align__(16) u16 Ps[4][16 * PADK];
  const int id = blockIdx.x;
  const int qt = 31 - (id >> 5);  // longest blocks first
  const int combo = id & 31;
  const int head = combo >> 1, b = combo & 1;
  const int tid = threadIdx.x;
  const int w = tid >> 6, lane = tid & 63;
  const int quad = lane >> 4, l16 = lane & 15;
  const int q0 = qt * 64;
  const size_t tokB = (size_t)b * 2048;

  short8 aq[2];
#pragma unroll
  for (int ks = 0; ks < 2; ++ks)
    aq[ks] = *(const short8*)(qk + (tokB + q0 + w * 16 + l16) * 2048 +
                              head * 64 + ks * 32 + quad * 8);

  const u16* kbase = qk + tokB * 2048 + 1024 + head * 64;   // + (kk0+row)*2048 + seg*8
  const u16* vbase = vT + (size_t)head * 64 * 4096 + tokB;  // + row*4096 + kk0 + seg*8

  float m_st[4] = {-1e30f, -1e30f, -1e30f, -1e30f};
  float l_st[4] = {0.f, 0.f, 0.f, 0.f};
  float4v o_acc[4] = {};

  for (int kt = 0; kt <= qt; ++kt) {
    const int kk0 = kt * 64;
    __syncthreads();
#pragma unroll
    for (int i = 0; i < 2; ++i) {
      int flat = tid * 2 + i;  // 0..511
      int row = flat >> 3, seg = flat & 7;
      *(short8*)(Ks + row * PADK + seg * 8) =
          *(const short8*)(kbase + (size_t)(kk0 + row) * 2048 + seg * 8);
      *(short8*)(Vt + row * PADK + seg * 8) =
          *(const short8*)(vbase + (size_t)row * 4096 + kk0 + seg * 8);
    }
    __syncthreads();

    float4v s[4];
#pragma unroll
    for (int fj = 0; fj < 4; ++fj) {
      float4v t = {0.f, 0.f, 0.f, 0.f};
#pragma unroll
      for (int ks = 0; ks < 2; ++ks) {
        short8 bk = *(const short8*)(Ks + (fj * 16 + l16) * PADK + ks * 32 + quad * 8);
        t = __builtin_amdgcn_mfma_f32_16x16x32_bf16(aq[ks], bk, t, 0, 0, 0);
      }
      s[fj] = t;
    }
#pragma unroll
    for (int fj = 0; fj < 4; ++fj)
#pragma unroll
      for (int r = 0; r < 4; ++r) s[fj][r] *= C2;
    if (kt == qt) {
#pragma unroll
      for (int fj = 0; fj < 4; ++fj) {
        int col = kk0 + fj * 16 + l16;
#pragma unroll
        for (int r = 0; r < 4; ++r) {
          int row = q0 + w * 16 + quad * 4 + r;
          if (col > row) s[fj][r] = -1e30f;
        }
      }
    }
    float mx[4];
#pragma unroll
    for (int r = 0; r < 4; ++r) {
      float m = s[0][r];
#pragma unroll
      for (int fj = 1; fj < 4; ++fj) m = fmaxf(m, s[fj][r]);
      m = fmaxf(m, __shfl_xor(m, 1));
      m = fmaxf(m, __shfl_xor(m, 2));
      m = fmaxf(m, __shfl_xor(m, 4));
      m = fmaxf(m, __shfl_xor(m, 8));
      mx[r] = m;
    }
    float alpha[4];
#pragma unroll
    for (int r = 0; r < 4; ++r) {
      float mnew = fmaxf(m_st[r], mx[r]);
      alpha[r] = __builtin_amdgcn_exp2f(m_st[r] - mnew);
      m_st[r] = mnew;
    }
    float rs[4] = {0.f, 0.f, 0.f, 0.f};
#pragma unroll
    for (int fj = 0; fj < 4; ++fj)
#pragma unroll
      for (int r = 0; r < 4; ++r) {
        float pv = __builtin_amdgcn_exp2f(s[fj][r] - m_st[r]);
        s[fj][r] = pv;
        rs[r] += pv;
      }
#pragma unroll
    for (int r = 0; r < 4; ++r) {
      float t = rs[r];
      t += __shfl_xor(t, 1);
      t += __shfl_xor(t, 2);
      t += __shfl_xor(t, 4);
      t += __shfl_xor(t, 8);
      l_st[r] = l_st[r] * alpha[r] + t;
    }
#pragma unroll
    for (int fj = 0; fj < 4; ++fj)
#pragma unroll
      for (int r = 0; r < 4; ++r) o_acc[fj][r] *= alpha[r];
#pragma unroll
    for (int fj = 0; fj < 4; ++fj)
#pragma unroll
      for (int r = 0; r < 4; ++r)
        Ps[w][(quad * 4 + r) * PADK + fj * 16 + l16] = f2bf(s[fj][r]);
    short8 ap[2];
#pragma unroll
    for (int ks = 0; ks < 2; ++ks)
      ap[ks] = *(const short8*)(&Ps[w][l16 * PADK + ks * 32 + quad * 8]);
#pragma unroll
    for (int fj = 0; fj < 4; ++fj)
#pragma unroll
      for (int ks = 0; ks < 2; ++ks) {
        short8 bv = *(const short8*)(Vt + (fj * 16 + l16) * PADK + ks * 32 + quad * 8);
        o_acc[fj] = __builtin_amdgcn_mfma_f32_16x16x32_bf16(ap[ks], bv, o_acc[fj], 0, 0, 0);
      }
  }
#pragma unroll
  for (int r = 0; r < 4; ++r) {
    float inv = 1.0f / l_st[r];
    int row = q0 + w * 16 + quad * 4 + r;
#pragma unroll
    for (int fj = 0; fj < 4; ++fj)
      qk[(tokB + row) * 2048 + head * 64 + fj * 16 + l16] =
          f2bf(o_acc[fj][r] * inv);
  }
}

// ---------------- launcher ----------------
extern "C" void kernel_launch(void* const* d_in, const int* in_sizes, int n_in,
                              void* d_out, int out_size, void* d_ws, size_t ws_size,
                              hipStream_t stream) {
  const float* x = (const float*)d_in[0];
  const float* W_Q = (const float*)d_in[1];
  const float* W_K = (const float*)d_in[2];
  const float* W_V = (const float*)d_in[3];
  const float* W_O = (const float*)d_in[4];
  const float* b_Q = (const float*)d_in[5];
  const float* b_K = (const float*)d_in[6];
  const float* b_V = (const float*)d_in[7];
  const float* b_O = (const float*)d_in[8];
  const float* W_in = (const float*)d_in[9];
  const float* b_in = (const float*)d_in[10];
  const float* W_out = (const float*)d_in[11];
  const float* b_out = (const float*)d_in[12];
  float* out = (float*)d_out;

  char* ws = (char*)d_ws;
  u16* Wqkv = (u16*)(ws);                 // [0, 6291456)
  u16* Wot  = (u16*)(ws + 6291456);       // [6291456, 8388608)
  u16* Wib  = (u16*)(ws + 8388608);       // [8388608, 16777216)
  u16* Wob  = (u16*)(ws + 16777216);      // [16777216, 25165824)
  float* bqkv = (float*)(ws + 25165824);  // [25165824, 25178112)
  u16* xn   = (u16*)(ws + 25178112);      // [25178112, 33566720)
  u16* qk   = (u16*)(ws + 33566720);      // [33566720, 50343936)  4096*2048 bf16
  u16* vT   = (u16*)(ws + 50343936);      // [50343936, 58732544)  1024*4096 bf16
  u16* hbuf = (u16*)(ws + 33566720);      // overlays qk+vT, 4096*4096, ends 67121152
  float* rm = (float*)(ws + 67121152);    // [67121152, 83898368)

  cvt_bf16<<<512, 256, 0, stream>>>(W_Q, Wqkv);
  cvt_bf16<<<512, 256, 0, stream>>>(W_K, Wqkv + 1048576);
  cvt_bf16<<<512, 256, 0, stream>>>(W_V, Wqkv + 2097152);
  cvt_bf16<<<2048, 256, 0, stream>>>(W_in, Wib);
  cvt_bf16<<<2048, 256, 0, stream>>>(W_out, Wob);
  prep_wo<<<512, 256, 0, stream>>>(W_O, Wot);
  prep_bqkv<<<12, 256, 0, stream>>>(b_Q, b_K, b_V, bqkv);

  ln_f32<<<4096, 256, 0, stream>>>(x, xn);
  // QKV: Q,K -> qk[4096][2048]; V -> vT[1024][4096] (transposed in epilogue)
  gemm_bt<128, 32, false, true, u16, float><<<dim3(32, 24), 256, 0, stream>>>(
      xn, Wqkv, bqkv, (const float*)nullptr, qk, vT, 4096, 3072, 1024, 1024, 2048);
  attn_flash<<<1024, 256, 0, stream>>>(qk, vT);
  // attn-out: BN=64, BK=64
  gemm_bt<64, 64, false, false, float, float><<<dim3(32, 16), 256, 0, stream>>>(
      qk /*z in q half, lda=2048*/, Wot, b_O, x, rm, nullptr, 4096, 1024, 1024, 2048, 1024);
  ln_f32<<<4096, 256, 0, stream>>>(rm, xn);
  gemm_bt<128, 32, true, false, u16, float><<<dim3(32, 32), 256, 0, stream>>>(
      xn, Wib, b_in, (const float*)nullptr, hbuf, nullptr, 4096, 4096, 1024, 1024, 4096);
  // MLP-out: BN=64, BK=64
  gemm_bt<64, 64, false, false, float, float><<<dim3(32, 16), 256, 0, stream>>>(
      hbuf, Wob, b_out, rm, out, nullptr, 4096, 1024, 4096, 4096, 1024);
}